// Round 1
// baseline (241.357 us; speedup 1.0000x reference)
//
#include <hip/hip_runtime.h>

// TensorProduct: N=200000, MUL=128.
// x1: (N,512) f32  -> x1_0 = x1[:, :128], x1_1 = x1[:,128:].reshape(N,3,128)
// x2: (N,4)   f32  -> y0 = x2[:,0], y1 = x2[:,1:4]
// w : (N,640) f32  -> w[:,5,128] * (1/sqrt(128))
// out: (N,512) f32 -> [out0 (128) | out1 (3,128)]
//
// Memory-bound: 6672 B/row, ~1.33 GB total. One float4 per thread per segment:
// 32 lanes/row, 8 rows per 256-thread block.

__global__ __launch_bounds__(256) void TensorProduct_75883482186070_kernel(
    const float* __restrict__ x1,
    const float* __restrict__ x2,
    const float* __restrict__ wts,
    float* __restrict__ out,
    int N)
{
    constexpr float S    = 0.0883883476483184406f;  // 1/sqrt(128)
    constexpr float ISQ3 = 0.5773502691896257645f;  // 1/sqrt(3)
    constexpr float ISQ2 = 0.7071067811865475244f;  // 1/sqrt(2)

    const int tid = blockIdx.x * 256 + threadIdx.x;
    const int n = tid >> 5;        // row index (32 lanes per row)
    if (n >= N) return;
    const int v = tid & 31;        // float4 index within 128-wide segment

    const float4* __restrict__ x1r = reinterpret_cast<const float4*>(x1) + (size_t)n * 128 + v;
    const float4* __restrict__ wr  = reinterpret_cast<const float4*>(wts) + (size_t)n * 160 + v;
    float4* __restrict__ outr      = reinterpret_cast<float4*>(out) + (size_t)n * 128 + v;

    // Broadcast scalars for this row (same float4 for all 32 lanes -> L1 hit)
    const float4 y = reinterpret_cast<const float4*>(x2)[n];
    const float y0  = y.x;
    const float y1a = y.y, y1b = y.z, y1c = y.w;

    // Coalesced float4 loads; segments are 32 float4 (=128 floats) apart.
    const float4 x10  = x1r[0];
    const float4 x11a = x1r[32];
    const float4 x11b = x1r[64];
    const float4 x11c = x1r[96];
    const float4 w0 = wr[0];
    const float4 w1 = wr[32];
    const float4 w2 = wr[64];
    const float4 w3 = wr[96];
    const float4 w4 = wr[128];

    float4 o0, ok0, ok1, ok2;

#define COMP(c)                                                              \
    {                                                                        \
        const float a0 = x10.c, a1 = x11a.c, a2 = x11b.c, a3 = x11c.c;       \
        const float W0 = w0.c * S, W1 = w1.c * S, W2 = w2.c * S;             \
        const float W3 = w3.c * (S * ISQ3), W4 = w4.c * (S * ISQ2);          \
        o0.c  = W0 * a0 * y0 + W3 * (a1 * y1a + a2 * y1b + a3 * y1c);        \
        ok0.c = W1 * a0 * y1a + W2 * a1 * y0 + W4 * (a2 * y1c - a3 * y1b);   \
        ok1.c = W1 * a0 * y1b + W2 * a2 * y0 + W4 * (a3 * y1a - a1 * y1c);   \
        ok2.c = W1 * a0 * y1c + W2 * a3 * y0 + W4 * (a1 * y1b - a2 * y1a);   \
    }
    COMP(x)
    COMP(y)
    COMP(z)
    COMP(w)
#undef COMP

    outr[0]  = o0;
    outr[32] = ok0;
    outr[64] = ok1;
    outr[96] = ok2;
}

extern "C" void kernel_launch(void* const* d_in, const int* in_sizes, int n_in,
                              void* d_out, int out_size, void* d_ws, size_t ws_size,
                              hipStream_t stream) {
    const float* x1  = (const float*)d_in[0];
    const float* x2  = (const float*)d_in[1];
    const float* wts = (const float*)d_in[2];
    float* out = (float*)d_out;

    const int N = in_sizes[1] / 4;          // x2 has 4 floats per row
    const int total_threads = N * 32;       // 32 lanes per row
    const int blocks = (total_threads + 255) / 256;

    TensorProduct_75883482186070_kernel<<<blocks, 256, 0, stream>>>(x1, x2, wts, out, N);
}

// Round 2
// 210.351 us; speedup vs baseline: 1.1474x; 1.1474x over previous
//
#include <hip/hip_runtime.h>

// TensorProduct: N=200000, MUL=128.
// x1: (N,512) f32  -> x1_0 = x1[:, :128], x1_1 = x1[:,128:].reshape(N,3,128)
// x2: (N,4)   f32  -> y0 = x2[:,0], y1 = x2[:,1:4]
// w : (N,640) f32  -> w[:,5,128] * (1/sqrt(128))
// out: (N,512) f32 -> [out0 (128) | out1 (3,128)]
//
// Memory-bound streaming: 6672 B/row, ~1.33 GB total, zero reuse except x2.
// One float4 lane per (row, 4-u chunk): 32 lanes/row.
// R1: 241.4 us (5.53 TB/s). R2: nontemporal loads/stores to stream past L2.

typedef float f32x4 __attribute__((ext_vector_type(4)));

__global__ __launch_bounds__(256) void TensorProduct_75883482186070_kernel(
    const float* __restrict__ x1,
    const float* __restrict__ x2,
    const float* __restrict__ wts,
    float* __restrict__ out,
    int N)
{
    constexpr float S    = 0.0883883476483184406f;  // 1/sqrt(128)
    constexpr float ISQ3 = 0.5773502691896257645f;  // 1/sqrt(3)
    constexpr float ISQ2 = 0.7071067811865475244f;  // 1/sqrt(2)

    const int tid = blockIdx.x * 256 + threadIdx.x;
    const int n = tid >> 5;        // row index (32 lanes per row)
    if (n >= N) return;
    const int v = tid & 31;        // float4 index within 128-wide segment

    const f32x4* __restrict__ x1r = reinterpret_cast<const f32x4*>(x1) + (size_t)n * 128 + v;
    const f32x4* __restrict__ wr  = reinterpret_cast<const f32x4*>(wts) + (size_t)n * 160 + v;
    f32x4* __restrict__ outr      = reinterpret_cast<f32x4*>(out) + (size_t)n * 128 + v;

    // Broadcast scalars for this row (32-lane reuse -> keep cached, no nt)
    const f32x4 y = reinterpret_cast<const f32x4*>(x2)[n];
    const float y0  = y.x;
    const float y1a = y.y, y1b = y.z, y1c = y.w;

    // Streamed once -> nontemporal. Coalesced 16B/lane, 512B per row-segment.
    const f32x4 x10  = __builtin_nontemporal_load(x1r);
    const f32x4 x11a = __builtin_nontemporal_load(x1r + 32);
    const f32x4 x11b = __builtin_nontemporal_load(x1r + 64);
    const f32x4 x11c = __builtin_nontemporal_load(x1r + 96);
    const f32x4 w0 = __builtin_nontemporal_load(wr);
    const f32x4 w1 = __builtin_nontemporal_load(wr + 32);
    const f32x4 w2 = __builtin_nontemporal_load(wr + 64);
    const f32x4 w3 = __builtin_nontemporal_load(wr + 96);
    const f32x4 w4 = __builtin_nontemporal_load(wr + 128);

    f32x4 o0, ok0, ok1, ok2;

#pragma unroll
    for (int c = 0; c < 4; ++c) {
        const float a0 = x10[c], a1 = x11a[c], a2 = x11b[c], a3 = x11c[c];
        const float W0 = w0[c] * S, W1 = w1[c] * S, W2 = w2[c] * S;
        const float W3 = w3[c] * (S * ISQ3), W4 = w4[c] * (S * ISQ2);
        o0[c]  = W0 * a0 * y0 + W3 * (a1 * y1a + a2 * y1b + a3 * y1c);
        ok0[c] = W1 * a0 * y1a + W2 * a1 * y0 + W4 * (a2 * y1c - a3 * y1b);
        ok1[c] = W1 * a0 * y1b + W2 * a2 * y0 + W4 * (a3 * y1a - a1 * y1c);
        ok2[c] = W1 * a0 * y1c + W2 * a3 * y0 + W4 * (a1 * y1b - a2 * y1a);
    }

    __builtin_nontemporal_store(o0,  outr);
    __builtin_nontemporal_store(ok0, outr + 32);
    __builtin_nontemporal_store(ok1, outr + 64);
    __builtin_nontemporal_store(ok2, outr + 96);
}

extern "C" void kernel_launch(void* const* d_in, const int* in_sizes, int n_in,
                              void* d_out, int out_size, void* d_ws, size_t ws_size,
                              hipStream_t stream) {
    const float* x1  = (const float*)d_in[0];
    const float* x2  = (const float*)d_in[1];
    const float* wts = (const float*)d_in[2];
    float* out = (float*)d_out;

    const int N = in_sizes[1] / 4;          // x2 has 4 floats per row
    const int total_threads = N * 32;       // 32 lanes per row
    const int blocks = (total_threads + 255) / 256;

    TensorProduct_75883482186070_kernel<<<blocks, 256, 0, stream>>>(x1, x2, wts, out, N);
}